// Round 7
// baseline (138.069 us; speedup 1.0000x reference)
//
#include <hip/hip_runtime.h>

// Shapes: B=1, N=4096, C=256, H=8, d=32.
// ws layout (ushort elems):
//   Q[2][8][4096][32]          @ 0         (Q pre-scaled by d^-0.5*log2e)
//   K[2][8][4096][32]          @ KOFF
//   Vb[2][8][128][2][512]      @ VOFF      (V in PV B-frag LINEAR order:
//                                           per 32-key block kb, per 16-d tile,
//                                           elem (d_lo, slot) at
//                                           ((slot>>3)*16+d_lo)*8 + (slot&7))
//   (WBF region no longer used: W is converted per-block into LDS — R22)

typedef __attribute__((ext_vector_type(8))) short short8;
typedef __attribute__((ext_vector_type(4))) float float4v;
typedef __attribute__((ext_vector_type(4))) unsigned int uint4v;

#define NTOK 4096
#define CDIM 256
#define HEADS 8
#define DHEAD 32

#define QOFF 0
#define KOFF (2*HEADS*NTOK*DHEAD)
#define VOFF (2*(2*HEADS*NTOK*DHEAD))

__device__ inline unsigned short f2bf(float f) {
    union { float f; unsigned u; } v; v.f = f;
    unsigned r = v.u + 0x7FFFu + ((v.u >> 16) & 1u);   // RNE
    return (unsigned short)(r >> 16);
}

// exp2 + truncation-pack two S tiles (8 floats) into one PV A-fragment
__device__ inline short8 exp_pack(float4v S0, float4v S1) {
    union { float f; unsigned u; } u0,u1,u2,u3,u4,u5,u6,u7;
    u0.f = __builtin_amdgcn_exp2f(S0[0]);
    u1.f = __builtin_amdgcn_exp2f(S0[1]);
    u2.f = __builtin_amdgcn_exp2f(S0[2]);
    u3.f = __builtin_amdgcn_exp2f(S0[3]);
    u4.f = __builtin_amdgcn_exp2f(S1[0]);
    u5.f = __builtin_amdgcn_exp2f(S1[1]);
    u6.f = __builtin_amdgcn_exp2f(S1[2]);
    u7.f = __builtin_amdgcn_exp2f(S1[3]);
    union { short8 s8; uint4v u4v; } p;
    p.u4v[0] = __builtin_amdgcn_perm(u1.u, u0.u, 0x07060302u);
    p.u4v[1] = __builtin_amdgcn_perm(u3.u, u2.u, 0x07060302u);
    p.u4v[2] = __builtin_amdgcn_perm(u5.u, u4.u, 0x07060302u);
    p.u4v[3] = __builtin_amdgcn_perm(u7.u, u6.u, 0x07060302u);
    return p.s8;
}

// ---------------------------------------------------------------------------
// Kernel 1 (R22): fused Wconv + t = x @ W^T (bf16 MFMA) + LayerNorm over d=32.
// Mechanism attacked: qkv_ln was grid-limited to 4 blocks/CU (1024 blocks)
// and chained global-W-load -> MFMA -> LN -> store with no TLP to hide L2
// latency. Now: grid 1536 = (row-tile 0..127) x (o32-PAIR 0..11) -> exactly
// 6 blocks/CU resident, zero tail, 6 waves/SIMD (+50% latency hiding).
// Each block converts its own W slice (fp32 -> bf16, B-frag swizzle) into a
// 16 KB LDS buffer per o32 (2 barriers/o32) -> MFMA B-fragments come from
// LDS, not L2 (operand latency off the serial chain), and the separate
// wconv kernel + its launch gap are gone.
// XCD-pinned: the 12 op-blocks sharing a row-tile's x land on one XCD.
// ---------------------------------------------------------------------------
__global__ __launch_bounds__(256) void qkv_ln_kernel(
    const float* __restrict__ before, const float* __restrict__ after,
    const float* __restrict__ W,
    const float* __restrict__ gamma, const float* __restrict__ beta,
    unsigned short* __restrict__ ws)
{
    __shared__ __align__(16) unsigned short wlds[8192];   // 16 KB: one o32 slice

    // decode: xcd = bid&7; j = bid>>3; op = j%12; rthi = j/12; rt = rthi*8+xcd
    const int bid  = blockIdx.x;
    const int xcd  = bid & 7;
    const int j    = bid >> 3;          // 0..191
    const int op   = j % 12;            // o32-pair 0..11
    const int rthi = j / 12;            // 0..15
    const int rt   = rthi*8 + xcd;      // row-tile 0..127

    const int tid  = threadIdx.x;
    const int lane = tid & 63;
    const int w    = tid >> 6;
    const int quad = lane >> 4;
    const int l16  = lane & 15;

    const int mrow_frag = rt*64 + w*16 + l16;
    const int inp_f = mrow_frag >> 12;
    const int n_f   = mrow_frag & 4095;
    const float* x = inp_f ? after : before;

    short8 afrag[8];
#pragma unroll
    for (int kk = 0; kk < 8; kk++) {
        const float4* p = reinterpret_cast<const float4*>(x + n_f*CDIM + kk*32 + quad*8);
        float4 a = p[0], b = p[1];
        short8 f;
        f[0]=(short)f2bf(a.x); f[1]=(short)f2bf(a.y); f[2]=(short)f2bf(a.z); f[3]=(short)f2bf(a.w);
        f[4]=(short)f2bf(b.x); f[5]=(short)f2bf(b.y); f[6]=(short)f2bf(b.z); f[7]=(short)f2bf(b.w);
        afrag[kk] = f;
    }

    const float g0  = gamma[l16], g1  = gamma[16+l16];
    const float be0 = beta[l16],  be1 = beta[16+l16];
    const float cscale = 0.17677669529663687f * 1.4426950408889634f; // d^-0.5*log2e

    const int mrow_out  = rt*64 + w*16 + quad*4;
    const int inp_o     = mrow_out >> 12;
    const int n_o_base  = mrow_out & 4095;

    for (int o32 = op*2; o32 < op*2 + 2; o32++) {
        // ---- convert this o32's W slice (32 rows x 256 cols fp32) into LDS
        // in B-frag swizzled order: dst = (kk*2+(r>>4))*512 + (quad16*16+(r&15))*8
        __syncthreads();                          // protect LDS from prev reads
#pragma unroll
        for (int it = 0; it < 4; it++) {
            int item = it*256 + tid;              // 0..1023 = (r 0..31, oct 0..31)
            int r   = item >> 5, oct = item & 31;
            int Cc  = oct * 8;
            const float4* p = reinterpret_cast<const float4*>(W + (o32*32 + r)*CDIM + Cc);
            float4 a = p[0], b = p[1];
            short8 f;
            f[0]=(short)f2bf(a.x); f[1]=(short)f2bf(a.y); f[2]=(short)f2bf(a.z); f[3]=(short)f2bf(a.w);
            f[4]=(short)f2bf(b.x); f[5]=(short)f2bf(b.y); f[6]=(short)f2bf(b.z); f[7]=(short)f2bf(b.w);
            int kk = Cc >> 5, q4 = (Cc >> 3) & 3;
            int dst = (kk*2 + (r>>4))*512 + (q4*16 + (r&15))*8;
            *reinterpret_cast<short8*>(wlds + dst) = f;
        }
        __syncthreads();

        float4v acc0 = {0.f,0.f,0.f,0.f}, acc1 = {0.f,0.f,0.f,0.f};
#pragma unroll
        for (int kk = 0; kk < 8; kk++) {
            short8 b0 = *reinterpret_cast<const short8*>(wlds + (kk*2    )*512 + lane*8);
            short8 b1 = *reinterpret_cast<const short8*>(wlds + (kk*2 + 1)*512 + lane*8);
            acc0 = __builtin_amdgcn_mfma_f32_16x16x32_bf16(afrag[kk], b0, acc0, 0,0,0);
            acc1 = __builtin_amdgcn_mfma_f32_16x16x32_bf16(afrag[kk], b1, acc1, 0,0,0);
        }

        const int which = o32 >> 3;     // 0=q 1=k 2=v
        const int h     = o32 & 7;
        unsigned short* qk = ws + (which == 0 ? QOFF : KOFF) + ((inp_o*HEADS + h)*NTOK)*DHEAD;
        unsigned short* vb = ws + VOFF + ((inp_o*HEADS + h)*128)*1024;
        const float qs = (which == 0) ? cscale : 1.0f;

#pragma unroll
        for (int i = 0; i < 4; i++) {
            float sum = acc0[i] + acc1[i];
            float sq  = acc0[i]*acc0[i] + acc1[i]*acc1[i];
#pragma unroll
            for (int m = 1; m < 16; m <<= 1) {
                sum += __shfl_xor(sum, m);
                sq  += __shfl_xor(sq,  m);
            }
            float mu   = sum * (1.0f/32.0f);
            float var  = sq * (1.0f/32.0f) - mu*mu;
            float rstd = rsqrtf(var + 1e-5f);
            float v0 = ((acc0[i]-mu)*rstd*g0 + be0) * qs;
            float v1 = ((acc1[i]-mu)*rstd*g1 + be1) * qs;
            int n = n_o_base + i;
            if (which < 2) {
                qk[n*DHEAD + l16]      = f2bf(v0);
                qk[n*DHEAD + 16 + l16] = f2bf(v1);
            } else {
                // B-frag linear layout: key n -> block kb, slot within block;
                // elem (d_lo, slot) at ((slot>>3)*16 + d_lo)*8 + (slot&7)
                int kb = n >> 5, ki = n & 31;
                int slot = ((ki & 15) >> 2)*8 + (ki & 3) + ((ki >> 4) << 2);
                int off  = ((slot >> 3)*16 + l16)*8 + (slot & 7);
                vb[kb*1024 + off]       = f2bf(v0);   // d = l16   (tile 0)
                vb[kb*1024 + 512 + off] = f2bf(v1);   // d = 16+l16 (tile 1)
            }
        }
    }
}

// ---------------------------------------------------------------------------
// Kernel 2: cross attention — exact R15 structure (best measured: 48.2 µs).
// block = 4 waves = 4 KEY-QUARTERS (1024 keys each), each wave computes ALL
// 64 q-rows (4 Q-frags): each K/V load feeds 64 q (L1-return traffic is the
// co-limiter). S^T = K·Q^T lands as the PV A-fragment (register softmax,
// truncation pack, exact O/l cancellation); l rides the MFMA pipe (ones-B).
// Loads at use sites (R16/R17/R20/R21 all showed prefetch variants are
// neutral or worse — not latency-bound). One barrier: 4-way merge in LDS.
// grid 1024 flat, XCD-pinned (h,X).
// ---------------------------------------------------------------------------
__global__ __launch_bounds__(256, 4) void attn_kernel(
    const unsigned short* __restrict__ ws, float* __restrict__ out)
{
    __shared__ float comb[3][64][33];           // waves 1..3: [row][d0..31, l]

    // XCD-locality decode: xcd = b&7 -> combo = xcd*2 + (i>>6), qb = i&63
    const int b    = blockIdx.x;
    const int xcd  = b & 7;
    const int i_   = b >> 3;                    // 0..127
    const int combo = xcd*2 + (i_ >> 6);        // 0..15
    const int h  = combo & 7;
    const int X  = combo >> 3;
    const int qb = i_ & 63;                     // 64 q-rows per block

    const int qinp = 1 - X, kvinp = X;
    const int tid  = threadIdx.x;
    const int lane = tid & 63;
    const int w    = tid >> 6;                  // key-quarter 0..3
    const int quad = lane >> 4;
    const int l16  = lane & 15;

    const unsigned short* qbase = ws + QOFF + ((qinp*HEADS + h)*NTOK)*DHEAD;
    const unsigned short* kbase = ws + KOFF + ((kvinp*HEADS + h)*NTOK)*DHEAD;
    const unsigned short* vbase = ws + VOFF + ((kvinp*HEADS + h)*128)*1024;

    const int q0 = qb*64;
    // Q as B-operand: B[n=q=l16][k=d=quad*8+j] — 4 fragments cover 64 q
    short8 qf[4];
#pragma unroll
    for (int qi = 0; qi < 4; qi++)
        qf[qi] = *reinterpret_cast<const short8*>(qbase + (q0 + qi*16 + l16)*DHEAD + quad*8);

    // K as A-operand (coalesced 1KB); V as B-operand (B-frag-linear, 1KB/blk)
    const unsigned short* kp = kbase + (w*1024 + l16)*DHEAD + quad*8;
    const unsigned short* vp = vbase + (w*32)*1024 + lane*8;

    const short8 ones = {0x3F80,0x3F80,0x3F80,0x3F80,0x3F80,0x3F80,0x3F80,0x3F80};

    float4v O[4][2], L[4];
#pragma unroll
    for (int qi = 0; qi < 4; qi++) {
        O[qi][0] = (float4v){0,0,0,0};
        O[qi][1] = (float4v){0,0,0,0};
        L[qi]    = (float4v){0,0,0,0};
    }
    const float4v z = {0,0,0,0};

    for (int t = 0; t < 32; t++) {              // 32-key steps over the quarter
        short8 kf0 = *reinterpret_cast<const short8*>(kp + (t*32     )*DHEAD);
        short8 kf1 = *reinterpret_cast<const short8*>(kp + (t*32 + 16)*DHEAD);
        short8 v0  = *reinterpret_cast<const short8*>(vp + t*1024);
        short8 v1  = *reinterpret_cast<const short8*>(vp + t*1024 + 512);
#pragma unroll
        for (int qi = 0; qi < 4; qi++) {        // 4 independent chains
            float4v S0 = __builtin_amdgcn_mfma_f32_16x16x32_bf16(kf0, qf[qi], z, 0,0,0);
            float4v S1 = __builtin_amdgcn_mfma_f32_16x16x32_bf16(kf1, qf[qi], z, 0,0,0);
            short8 pf = exp_pack(S0, S1);
            O[qi][0] = __builtin_amdgcn_mfma_f32_16x16x32_bf16(pf, v0,   O[qi][0], 0,0,0);
            O[qi][1] = __builtin_amdgcn_mfma_f32_16x16x32_bf16(pf, v1,   O[qi][1], 0,0,0);
            L[qi]    = __builtin_amdgcn_mfma_f32_16x16x32_bf16(pf, ones, L[qi],    0,0,0);
        }
    }

    // merge the 4 key-quarters: waves 1..3 publish, wave 0 merges + writes.
    // L: row = q (quad*4+i within the qi tile), all cols equal.
    if (w > 0) {
#pragma unroll
        for (int qi = 0; qi < 4; qi++)
#pragma unroll
            for (int i = 0; i < 4; i++) {
                int row = qi*16 + quad*4 + i;
                comb[w-1][row][l16]      = O[qi][0][i];
                comb[w-1][row][16 + l16] = O[qi][1][i];
                if (l16 == 0) comb[w-1][row][32] = L[qi][i];
            }
    }
    __syncthreads();

    if (w == 0) {
        float* ob = out + (size_t)X*NTOK*CDIM + h*DHEAD;
#pragma unroll
        for (int qi = 0; qi < 4; qi++) {
#pragma unroll
            for (int i = 0; i < 4; i++) {
                int row = qi*16 + quad*4 + i;
                float l  = L[qi][i]    + comb[0][row][32]      + comb[1][row][32]      + comb[2][row][32];
                float a  = O[qi][0][i] + comb[0][row][l16]     + comb[1][row][l16]     + comb[2][row][l16];
                float bb = O[qi][1][i] + comb[0][row][16+l16]  + comb[1][row][16+l16]  + comb[2][row][16+l16];
                float inv = 1.0f / l;
                int orow = q0 + row;
                ob[orow*CDIM + l16]      = a  * inv;
                ob[orow*CDIM + 16 + l16] = bb * inv;
            }
        }
    }
}

extern "C" void kernel_launch(void* const* d_in, const int* in_sizes, int n_in,
                              void* d_out, int out_size, void* d_ws, size_t ws_size,
                              hipStream_t stream)
{
    const float* before = (const float*)d_in[0];
    const float* after  = (const float*)d_in[1];
    const float* W      = (const float*)d_in[2];
    const float* gamma  = (const float*)d_in[3];
    const float* beta   = (const float*)d_in[4];
    float* out          = (float*)d_out;
    unsigned short* ws  = (unsigned short*)d_ws;   // needs ~12.6 MB

    hipLaunchKernelGGL(qkv_ln_kernel, dim3(1536), dim3(256), 0, stream,
                       before, after, W, gamma, beta, ws);
    hipLaunchKernelGGL(attn_kernel, dim3(1024), dim3(256), 0, stream, ws, out);
}